// Round 1
// baseline (838.608 us; speedup 1.0000x reference)
//
#include <hip/hip_runtime.h>
#include <math.h>

#define N_NODES 50000
#define N_EDGES 800000

// ---------------- degree / CSR build ----------------

__global__ void k_degrees(const int* __restrict__ ei, int* __restrict__ deg_out,
                          int* __restrict__ deg_in) {
    int e = blockIdx.x * 256 + threadIdx.x;
    if (e < N_EDGES) {
        atomicAdd(&deg_out[ei[e]], 1);
        atomicAdd(&deg_in[ei[N_EDGES + e]], 1);
    }
}

__global__ void k_invsqrt(const int* __restrict__ deg_out, const int* __restrict__ deg_in,
                          float* __restrict__ inv_out, float* __restrict__ inv_in) {
    int n = blockIdx.x * 256 + threadIdx.x;
    if (n < N_NODES) {
        int a = deg_out[n]; if (a < 1) a = 1;
        int b = deg_in[n];  if (b < 1) b = 1;
        inv_out[n] = 1.0f / sqrtf((float)a);
        inv_in[n]  = 1.0f / sqrtf((float)b);
    }
}

// exclusive scan, 256-element blocks (Hillis-Steele)
__global__ void k_scan1(const int* __restrict__ in, int* __restrict__ out,
                        int* __restrict__ bsum, int n) {
    __shared__ int s[256];
    int i = blockIdx.x * 256 + threadIdx.x;
    int v = (i < n) ? in[i] : 0;
    s[threadIdx.x] = v;
    __syncthreads();
    for (int off = 1; off < 256; off <<= 1) {
        int t = (threadIdx.x >= off) ? s[threadIdx.x - off] : 0;
        __syncthreads();
        s[threadIdx.x] += t;
        __syncthreads();
    }
    if (i < n) out[i] = s[threadIdx.x] - v;   // exclusive
    if (threadIdx.x == 255 && bsum) bsum[blockIdx.x] = s[255];
}

__global__ void k_scan3(int* __restrict__ out, const int* __restrict__ bscan, int n) {
    int i = blockIdx.x * 256 + threadIdx.x;
    if (i < n) out[i] += bscan[blockIdx.x];
}

__global__ void k_bucket(const int* __restrict__ ei, const int* __restrict__ row_start,
                         int* __restrict__ cursor, int* __restrict__ src_sorted) {
    int e = blockIdx.x * 256 + threadIdx.x;
    if (e < N_EDGES) {
        int d = ei[N_EDGES + e];
        int p = row_start[d] + atomicAdd(&cursor[d], 1);
        src_sorted[p] = ei[e];
    }
}

// ---------------- aggregation ----------------

// thread-per-(node,feature) for small widths. Optional per-source scale,
// optional epilogue (x*inv_in + bias) used for the final layer.
template <int F, bool SCALE, bool EPI>
__global__ void k_agg_small(const float* __restrict__ feat, const float* __restrict__ scale_src,
                            const int* __restrict__ row_start, const int* __restrict__ deg,
                            const int* __restrict__ src_sorted, float* __restrict__ out,
                            const float* __restrict__ inv_in, const float* __restrict__ bias) {
    int idx = blockIdx.x * 256 + threadIdx.x;
    if (idx >= N_NODES * F) return;
    int n = idx / F;
    int f = idx - n * F;
    int e = row_start[n];
    int end = e + deg[n];
    float acc = 0.f;
    for (; e < end; ++e) {
        int s = src_sorted[e];
        float v = feat[s * F + f];
        if (SCALE) v *= scale_src[s];
        acc += v;
    }
    if (EPI) acc = acc * inv_in[n] + bias[f];
    out[idx] = acc;
}

// block-per-node, width 220 (h already pre-scaled by inv_sqrt_out)
__global__ __launch_bounds__(256) void k_agg220(const float* __restrict__ h,
                                                const int* __restrict__ row_start,
                                                const int* __restrict__ deg,
                                                const int* __restrict__ src_sorted,
                                                float* __restrict__ out) {
    int n = blockIdx.x;
    int t = threadIdx.x;
    if (t >= 220) return;   // no barriers below; early-exit is safe
    int e = row_start[n];
    int end = e + deg[n];
    float a0 = 0.f, a1 = 0.f, a2 = 0.f, a3 = 0.f;
    for (; e + 3 < end; e += 4) {
        int sa = src_sorted[e];
        int sb = src_sorted[e + 1];
        int sc = src_sorted[e + 2];
        int sd = src_sorted[e + 3];
        a0 += h[sa * 220 + t];
        a1 += h[sb * 220 + t];
        a2 += h[sc * 220 + t];
        a3 += h[sd * 220 + t];
    }
    for (; e < end; ++e) a0 += h[src_sorted[e] * 220 + t];
    out[n * 220 + t] = (a0 + a1) + (a2 + a3);
}

// ---------------- GEMM (fp32 vector ALU; Fout fixed = 220) ----------------
// out[n][j] = post[n] * tanh( inv_in[n]*(A[n,:] @ W)[j] + b[j] )
// Block: 64 rows x 220 cols. Lane layout: wave w (0..3), rg=(lane>>4) (0..3),
// cg=(lane&15). Lane owns rows w*16+rg*4+{0..3} and cols cg+16*{0..13}.
template <int K, int NKT>
__global__ __launch_bounds__(256, 4) void k_gemm(const float* __restrict__ A,
                                                 const float* __restrict__ W,
                                                 const float* __restrict__ bias,
                                                 const float* __restrict__ inv_in,
                                                 const float* __restrict__ post,
                                                 float* __restrict__ out) {
    constexpr int KT = K / NKT;        // 55 for K=220, 22 for K=22
    constexpr int LDSROW = 68;         // 64 rows + pad 4 (16B-aligned stride, spreads banks)
    __shared__ float s[KT][LDSROW];

    int tid = threadIdx.x;
    int l = tid & 63, w = tid >> 6;
    int rg = l >> 4;
    int cg = l & 15;
    int rloc = w * 16 + rg * 4;        // lane's 4 local rows
    int row0 = blockIdx.x * 64;

    float acc[4][14];
#pragma unroll
    for (int r = 0; r < 4; ++r)
#pragma unroll
        for (int c = 0; c < 14; ++c) acc[r][c] = 0.f;

    for (int kt = 0; kt < NKT; ++kt) {
        int k0 = kt * KT;
        // stage A^T tile, scaled by inv_in
        for (int idx = tid; idx < 64 * KT; idx += 256) {
            int r = idx / KT;
            int kk = idx - r * KT;
            int row = row0 + r;
            float v = 0.f;
            if (row < N_NODES) v = A[row * K + k0 + kk] * inv_in[row];
            s[kk][r] = v;
        }
        __syncthreads();
#pragma unroll 1
        for (int kk = 0; kk < KT; ++kk) {
            float4 a4 = *(const float4*)&s[kk][rloc];
            const float* wrow = &W[(k0 + kk) * 220];
#pragma unroll
            for (int c = 0; c < 14; ++c) {
                int j = cg + 16 * c;
                float wv = (j < 220) ? wrow[j] : 0.f;
                acc[0][c] += a4.x * wv;
                acc[1][c] += a4.y * wv;
                acc[2][c] += a4.z * wv;
                acc[3][c] += a4.w * wv;
            }
        }
        __syncthreads();
    }
#pragma unroll
    for (int r = 0; r < 4; ++r) {
        int row = row0 + rloc + r;
        if (row >= N_NODES) continue;
        float pv = post[row];
#pragma unroll
        for (int c = 0; c < 14; ++c) {
            int j = cg + 16 * c;
            if (j < 220) {
                float v = tanhf(acc[r][c] + bias[j]);
                out[row * 220 + j] = v * pv;
            }
        }
    }
}

// tmp10 = h @ W3   (h is h2 pre-scaled by inv_sqrt_out; matmul commutes with A^T)
__global__ void k_w3(const float* __restrict__ h, const float* __restrict__ W3,
                     float* __restrict__ tmp) {
    int idx = blockIdx.x * 256 + threadIdx.x;
    if (idx >= N_NODES * 10) return;
    int n = idx / 10;
    int j = idx - n * 10;
    const float* hr = &h[n * 220];
    float acc = 0.f;
#pragma unroll 4
    for (int k = 0; k < 220; ++k) acc += hr[k] * W3[k * 10 + j];
    tmp[idx] = acc;
}

// ---------------- launch ----------------

extern "C" void kernel_launch(void* const* d_in, const int* in_sizes, int n_in,
                              void* d_out, int out_size, void* d_ws, size_t ws_size,
                              hipStream_t stream) {
    const float* x  = (const float*)d_in[0];
    const float* W0 = (const float*)d_in[1];
    const float* b0 = (const float*)d_in[2];
    const float* W1 = (const float*)d_in[3];
    const float* b1 = (const float*)d_in[4];
    const float* W2 = (const float*)d_in[5];
    const float* b2 = (const float*)d_in[6];
    const float* W3 = (const float*)d_in[7];
    const float* b3 = (const float*)d_in[8];
    const int*   ei = (const int*)d_in[9];
    float* out = (float*)d_out;

    int* ws = (int*)d_ws;
    // word-offset layout (50176 = 50000 rounded up to x256)
    int* deg_out   = ws + 0;
    int* deg_in    = ws + 50176;
    int* cursor    = ws + 100352;
    int* row_start = ws + 150528;
    int* bsum      = ws + 200704;
    int* bscan     = ws + 200960;
    float* inv_out = (float*)(ws + 201216);
    float* inv_in  = (float*)(ws + 251392);
    int* src_sorted = ws + 301568;            // 800000
    float* agg  = (float*)(ws + 1101568);     // 50000*220 (also holds agg22 / tmp10)
    float* hbuf = (float*)(ws + 12101568);    // 50000*220

    // zero deg_out, deg_in, cursor (contiguous)
    hipMemsetAsync(ws, 0, (size_t)150528 * sizeof(int), stream);

    k_degrees<<<(N_EDGES + 255) / 256, 256, 0, stream>>>(ei, deg_out, deg_in);
    k_invsqrt<<<(N_NODES + 255) / 256, 256, 0, stream>>>(deg_out, deg_in, inv_out, inv_in);

    int nblk = (N_NODES + 255) / 256;   // 196
    k_scan1<<<nblk, 256, 0, stream>>>(deg_in, row_start, bsum, N_NODES);
    k_scan1<<<1, 256, 0, stream>>>(bsum, bscan, nullptr, nblk);
    k_scan3<<<nblk, 256, 0, stream>>>(row_start, bscan, N_NODES);
    k_bucket<<<(N_EDGES + 255) / 256, 256, 0, stream>>>(ei, row_start, cursor, src_sorted);

    // ---- layer 0: propagate x at width 22 (scaled by inv_out at gather), then GEMM
    k_agg_small<22, true, false><<<(N_NODES * 22 + 255) / 256, 256, 0, stream>>>(
        x, inv_out, row_start, deg_in, src_sorted, agg, nullptr, nullptr);
    k_gemm<22, 1><<<(N_NODES + 63) / 64, 256, 0, stream>>>(agg, W0, b0, inv_in, inv_out, hbuf);

    // ---- layer 1
    k_agg220<<<N_NODES, 256, 0, stream>>>(hbuf, row_start, deg_in, src_sorted, agg);
    k_gemm<220, 4><<<(N_NODES + 63) / 64, 256, 0, stream>>>(agg, W1, b1, inv_in, inv_out, hbuf);

    // ---- layer 2
    k_agg220<<<N_NODES, 256, 0, stream>>>(hbuf, row_start, deg_in, src_sorted, agg);
    k_gemm<220, 4><<<(N_NODES + 63) / 64, 256, 0, stream>>>(agg, W2, b2, inv_in, inv_out, hbuf);

    // ---- layer 3: GEMM first (width 10), then propagate + epilogue straight to d_out
    k_w3<<<(N_NODES * 10 + 255) / 256, 256, 0, stream>>>(hbuf, W3, agg);
    k_agg_small<10, false, true><<<(N_NODES * 10 + 255) / 256, 256, 0, stream>>>(
        agg, nullptr, row_start, deg_in, src_sorted, out, inv_in, b3);
}

// Round 2
// 788.256 us; speedup vs baseline: 1.0639x; 1.0639x over previous
//
#include <hip/hip_runtime.h>
#include <math.h>

#define N_NODES 50000
#define N_EDGES 800000

// ---------------- degree / CSR build ----------------

__global__ void k_degrees(const int* __restrict__ ei, int* __restrict__ deg_out,
                          int* __restrict__ deg_in) {
    int e = blockIdx.x * 256 + threadIdx.x;
    if (e < N_EDGES) {
        atomicAdd(&deg_out[ei[e]], 1);
        atomicAdd(&deg_in[ei[N_EDGES + e]], 1);
    }
}

__global__ void k_invsqrt(const int* __restrict__ deg_out, const int* __restrict__ deg_in,
                          float* __restrict__ inv_out, float* __restrict__ inv_in) {
    int n = blockIdx.x * 256 + threadIdx.x;
    if (n < N_NODES) {
        int a = deg_out[n]; if (a < 1) a = 1;
        int b = deg_in[n];  if (b < 1) b = 1;
        inv_out[n] = 1.0f / sqrtf((float)a);
        inv_in[n]  = 1.0f / sqrtf((float)b);
    }
}

// exclusive scan, 256-element blocks (Hillis-Steele)
__global__ void k_scan1(const int* __restrict__ in, int* __restrict__ out,
                        int* __restrict__ bsum, int n) {
    __shared__ int s[256];
    int i = blockIdx.x * 256 + threadIdx.x;
    int v = (i < n) ? in[i] : 0;
    s[threadIdx.x] = v;
    __syncthreads();
    for (int off = 1; off < 256; off <<= 1) {
        int t = (threadIdx.x >= off) ? s[threadIdx.x - off] : 0;
        __syncthreads();
        s[threadIdx.x] += t;
        __syncthreads();
    }
    if (i < n) out[i] = s[threadIdx.x] - v;   // exclusive
    if (threadIdx.x == 255 && bsum) bsum[blockIdx.x] = s[255];
}

__global__ void k_scan3(int* __restrict__ out, const int* __restrict__ bscan, int n) {
    int i = blockIdx.x * 256 + threadIdx.x;
    if (i < n) out[i] += bscan[blockIdx.x];
}

__global__ void k_bucket(const int* __restrict__ ei, const int* __restrict__ row_start,
                         int* __restrict__ cursor, int* __restrict__ src_sorted) {
    int e = blockIdx.x * 256 + threadIdx.x;
    if (e < N_EDGES) {
        int d = ei[N_EDGES + e];
        int p = row_start[d] + atomicAdd(&cursor[d], 1);
        src_sorted[p] = ei[e];
    }
}

// ---------------- fast tanh ----------------
// tanh(x) = 1 - 2/(e^{2x}+1). Saturates correctly: e^{2x}->inf => 1,
// e^{2x}->0 => -1. abs error ~1e-7 with v_exp/v_rcp approximations.
__device__ __forceinline__ float fast_tanh(float x) {
    float e = __expf(2.0f * x);
    float r = __builtin_amdgcn_rcpf(e + 1.0f);
    return 1.0f - 2.0f * r;
}

// ---------------- aggregation ----------------

template <int F, bool SCALE, bool EPI>
__global__ void k_agg_small(const float* __restrict__ feat, const float* __restrict__ scale_src,
                            const int* __restrict__ row_start, const int* __restrict__ deg,
                            const int* __restrict__ src_sorted, float* __restrict__ out,
                            const float* __restrict__ inv_in, const float* __restrict__ bias) {
    int idx = blockIdx.x * 256 + threadIdx.x;
    if (idx >= N_NODES * F) return;
    int n = idx / F;
    int f = idx - n * F;
    int e = row_start[n];
    int end = e + deg[n];
    float acc = 0.f;
    for (; e < end; ++e) {
        int s = src_sorted[e];
        float v = feat[s * F + f];
        if (SCALE) v *= scale_src[s];
        acc += v;
    }
    if (EPI) acc = acc * inv_in[n] + bias[f];
    out[idx] = acc;
}

// block-per-node, width 220 (h already pre-scaled by inv_sqrt_out)
__global__ __launch_bounds__(256) void k_agg220(const float* __restrict__ h,
                                                const int* __restrict__ row_start,
                                                const int* __restrict__ deg,
                                                const int* __restrict__ src_sorted,
                                                float* __restrict__ out) {
    int n = blockIdx.x;
    int t = threadIdx.x;
    if (t >= 220) return;   // no barriers below; early-exit is safe
    int e = row_start[n];
    int end = e + deg[n];
    float a0 = 0.f, a1 = 0.f, a2 = 0.f, a3 = 0.f;
    for (; e + 3 < end; e += 4) {
        int sa = src_sorted[e];
        int sb = src_sorted[e + 1];
        int sc = src_sorted[e + 2];
        int sd = src_sorted[e + 3];
        a0 += h[sa * 220 + t];
        a1 += h[sb * 220 + t];
        a2 += h[sc * 220 + t];
        a3 += h[sd * 220 + t];
    }
    for (; e < end; ++e) a0 += h[src_sorted[e] * 220 + t];
    out[n * 220 + t] = (a0 + a1) + (a2 + a3);
}

// ---------------- GEMM (fp32 vector ALU; Fout fixed = 220) ----------------
// out[n][j] = post[n] * tanh( inv_in[n]*(A[n,:] @ W)[j] + b[j] )
// 128 rows x 220 cols per 256-thread block. Both A-tile and W-tile staged in
// LDS (W from global was the round-1 latency bottleneck: 14 L2 loads per kk).
// Lane layout: wave w (0..3) owns rows w*32+rg*8..+7 (rg=lane>>4), cols
// cg+16*{0..13} (cg=lane&15). 112 FMA per kk vs 16 LDS instrs (2x b128 A,
// 14x b32 W broadcast, conflict-free).
// LDS: A 55*132*4=29.0KB + W 55*224*4=49.3KB = 78.3KB -> 2 blocks/CU.
template <int K, int NKT>
__global__ __launch_bounds__(256, 2) void k_gemm(const float* __restrict__ A,
                                                 const float* __restrict__ Wm,
                                                 const float* __restrict__ bias,
                                                 const float* __restrict__ inv_in,
                                                 const float* __restrict__ post,
                                                 float* __restrict__ out) {
    constexpr int KT = K / NKT;        // 55 for K=220, 22 for K=22
    constexpr int AS = 132;            // 128 rows + pad (multiple of 4 words for b128)
    constexpr int WS = 224;
    __shared__ float s_a[KT][AS];
    __shared__ float s_w[KT][WS];

    int tid = threadIdx.x;
    int l = tid & 63, w = tid >> 6;
    int rg = l >> 4;
    int cg = l & 15;
    int rbase = w * 32 + rg * 8;       // lane's 8 contiguous local rows
    int row0 = blockIdx.x * 128;

    float acc[8][14];
#pragma unroll
    for (int r = 0; r < 8; ++r)
#pragma unroll
        for (int c = 0; c < 14; ++c) acc[r][c] = 0.f;

    for (int kt = 0; kt < NKT; ++kt) {
        int k0 = kt * KT;
        // stage A^T tile, scaled by inv_in (coalesced 55-word runs)
        for (int idx = tid; idx < 128 * KT; idx += 256) {
            int r = idx / KT;
            int kk = idx - r * KT;
            int row = row0 + r;
            float v = 0.f;
            if (row < N_NODES) v = A[row * K + k0 + kk] * inv_in[row];
            s_a[kk][r] = v;
        }
        // stage W tile (fully contiguous global reads)
        for (int idx = tid; idx < KT * 220; idx += 256) {
            int kk = idx / 220;
            int j = idx - kk * 220;
            s_w[kk][j] = Wm[(k0 + kk) * 220 + j];
        }
        __syncthreads();
#pragma unroll 2
        for (int kk = 0; kk < KT; ++kk) {
            float4 a0 = *(const float4*)&s_a[kk][rbase];
            float4 a1 = *(const float4*)&s_a[kk][rbase + 4];
#pragma unroll
            for (int c = 0; c < 14; ++c) {
                float wv = s_w[kk][cg + 16 * c];   // cols >=220 read junk; masked at store
                acc[0][c] += a0.x * wv;
                acc[1][c] += a0.y * wv;
                acc[2][c] += a0.z * wv;
                acc[3][c] += a0.w * wv;
                acc[4][c] += a1.x * wv;
                acc[5][c] += a1.y * wv;
                acc[6][c] += a1.z * wv;
                acc[7][c] += a1.w * wv;
            }
        }
        __syncthreads();
    }

    // epilogue: bias + tanh + inv_sqrt_out pre-scale for next layer
    float bv[14];
#pragma unroll
    for (int c = 0; c < 14; ++c) {
        int j = cg + 16 * c;
        bv[c] = (j < 220) ? bias[j] : 0.f;
    }
#pragma unroll
    for (int r = 0; r < 8; ++r) {
        int row = row0 + rbase + r;
        if (row >= N_NODES) continue;
        float pv = post[row];
#pragma unroll
        for (int c = 0; c < 14; ++c) {
            int j = cg + 16 * c;
            if (j < 220) {
                out[row * 220 + j] = pv * fast_tanh(acc[r][c] + bv[c]);
            }
        }
    }
}

// tmp10 = h @ W3   (h is h2 pre-scaled by inv_sqrt_out; matmul commutes with A^T)
__global__ void k_w3(const float* __restrict__ h, const float* __restrict__ W3,
                     float* __restrict__ tmp) {
    int idx = blockIdx.x * 256 + threadIdx.x;
    if (idx >= N_NODES * 10) return;
    int n = idx / 10;
    int j = idx - n * 10;
    const float2* hr = (const float2*)&h[n * 220];   // rows are 8B-aligned (880B stride)
    float acc = 0.f;
#pragma unroll 10
    for (int k2 = 0; k2 < 110; ++k2) {
        float2 hv = hr[k2];
        acc += hv.x * W3[(2 * k2) * 10 + j];
        acc += hv.y * W3[(2 * k2 + 1) * 10 + j];
    }
    tmp[idx] = acc;
}

// ---------------- launch ----------------

extern "C" void kernel_launch(void* const* d_in, const int* in_sizes, int n_in,
                              void* d_out, int out_size, void* d_ws, size_t ws_size,
                              hipStream_t stream) {
    const float* x  = (const float*)d_in[0];
    const float* W0 = (const float*)d_in[1];
    const float* b0 = (const float*)d_in[2];
    const float* W1 = (const float*)d_in[3];
    const float* b1 = (const float*)d_in[4];
    const float* W2 = (const float*)d_in[5];
    const float* b2 = (const float*)d_in[6];
    const float* W3 = (const float*)d_in[7];
    const float* b3 = (const float*)d_in[8];
    const int*   ei = (const int*)d_in[9];
    float* out = (float*)d_out;

    int* ws = (int*)d_ws;
    // word-offset layout (50176 = 50000 rounded up to x256)
    int* deg_out   = ws + 0;
    int* deg_in    = ws + 50176;
    int* cursor    = ws + 100352;
    int* row_start = ws + 150528;
    int* bsum      = ws + 200704;
    int* bscan     = ws + 200960;
    float* inv_out = (float*)(ws + 201216);
    float* inv_in  = (float*)(ws + 251392);
    int* src_sorted = ws + 301568;            // 800000
    float* agg  = (float*)(ws + 1101568);     // 50000*220 (also holds agg22 / tmp10)
    float* hbuf = (float*)(ws + 12101568);    // 50000*220

    // zero deg_out, deg_in, cursor (contiguous)
    hipMemsetAsync(ws, 0, (size_t)150528 * sizeof(int), stream);

    k_degrees<<<(N_EDGES + 255) / 256, 256, 0, stream>>>(ei, deg_out, deg_in);
    k_invsqrt<<<(N_NODES + 255) / 256, 256, 0, stream>>>(deg_out, deg_in, inv_out, inv_in);

    int nblk = (N_NODES + 255) / 256;   // 196
    k_scan1<<<nblk, 256, 0, stream>>>(deg_in, row_start, bsum, N_NODES);
    k_scan1<<<1, 256, 0, stream>>>(bsum, bscan, nullptr, nblk);
    k_scan3<<<nblk, 256, 0, stream>>>(row_start, bscan, N_NODES);
    k_bucket<<<(N_EDGES + 255) / 256, 256, 0, stream>>>(ei, row_start, cursor, src_sorted);

    int gemm_grid = (N_NODES + 127) / 128;   // 391

    // ---- layer 0: propagate x at width 22 (scaled by inv_out at gather), then GEMM
    k_agg_small<22, true, false><<<(N_NODES * 22 + 255) / 256, 256, 0, stream>>>(
        x, inv_out, row_start, deg_in, src_sorted, agg, nullptr, nullptr);
    k_gemm<22, 1><<<gemm_grid, 256, 0, stream>>>(agg, W0, b0, inv_in, inv_out, hbuf);

    // ---- layer 1
    k_agg220<<<N_NODES, 256, 0, stream>>>(hbuf, row_start, deg_in, src_sorted, agg);
    k_gemm<220, 4><<<gemm_grid, 256, 0, stream>>>(agg, W1, b1, inv_in, inv_out, hbuf);

    // ---- layer 2
    k_agg220<<<N_NODES, 256, 0, stream>>>(hbuf, row_start, deg_in, src_sorted, agg);
    k_gemm<220, 4><<<gemm_grid, 256, 0, stream>>>(agg, W2, b2, inv_in, inv_out, hbuf);

    // ---- layer 3: GEMM first (width 10), then propagate + epilogue straight to d_out
    k_w3<<<(N_NODES * 10 + 255) / 256, 256, 0, stream>>>(hbuf, W3, agg);
    k_agg_small<10, false, true><<<(N_NODES * 10 + 255) / 256, 256, 0, stream>>>(
        agg, nullptr, row_start, deg_in, src_sorted, out, inv_in, b3);
}